// Round 3
// baseline (1183.453 us; speedup 1.0000x reference)
//
#include <hip/hip_runtime.h>

typedef float f32x4 __attribute__((ext_vector_type(4)));
typedef short bf16x8 __attribute__((ext_vector_type(8)));
typedef unsigned short ushort_t;
typedef unsigned int uint_t;

// ---------------- Threefry-2x32 (20 rounds), exact JAX semantics (verified r1) ----------------
__device__ __forceinline__ unsigned rotl32(unsigned x, unsigned r){ return (x << r) | (x >> (32u - r)); }

__device__ __forceinline__ void tf2x32(unsigned k0, unsigned k1, unsigned c0, unsigned c1,
                                       unsigned &o0, unsigned &o1){
  unsigned ks2 = k0 ^ k1 ^ 0x1BD11BDAu;
  unsigned x0 = c0 + k0, x1 = c1 + k1;
#define TFR(r) { x0 += x1; x1 = rotl32(x1, r); x1 ^= x0; }
  TFR(13) TFR(15) TFR(26) TFR(6)
  x0 += k1;  x1 += ks2 + 1u;
  TFR(17) TFR(29) TFR(16) TFR(24)
  x0 += ks2; x1 += k0 + 2u;
  TFR(13) TFR(15) TFR(26) TFR(6)
  x0 += k0;  x1 += k1 + 3u;
  TFR(17) TFR(29) TFR(16) TFR(24)
  x0 += k1;  x1 += ks2 + 4u;
  TFR(13) TFR(15) TFR(26) TFR(6)
  x0 += ks2; x1 += k0 + 5u;
#undef TFR
  o0 = x0; o1 = x1;
}

__device__ __forceinline__ float bits_to_u01(unsigned bits){
  return __uint_as_float((bits >> 9) | 0x3f800000u) - 1.0f;
}

// XLA ErfInv32 (Giles polynomial) — verified r1
__device__ __forceinline__ float erfinv_f(float x){
  float w = -log1pf(-x * x);
  float p;
  if (w < 5.0f){
    w -= 2.5f;
    p = 2.81022636e-08f;
    p = 3.43273939e-07f + p * w;
    p = -3.5233877e-06f + p * w;
    p = -4.39150654e-06f + p * w;
    p = 0.00021858087f + p * w;
    p = -0.00125372503f + p * w;
    p = -0.00417768164f + p * w;
    p = 0.246640727f + p * w;
    p = 1.50140941f + p * w;
  } else {
    w = sqrtf(w) - 3.0f;
    p = -0.000200214257f;
    p = 0.000100950558f + p * w;
    p = 0.00134934322f + p * w;
    p = -0.00367342844f + p * w;
    p = 0.00573950773f + p * w;
    p = -0.0076224613f + p * w;
    p = 0.00943887047f + p * w;
    p = 1.00167406f + p * w;
    p = 2.83297682f + p * w;
  }
  return p * x;
}

__device__ __forceinline__ ushort_t f2bf(float f){
  unsigned u = __float_as_uint(f);
  unsigned r = u + 0x7fffu + ((u >> 16) & 1u);
  return (ushort_t)(r >> 16);
}
__device__ __forceinline__ float bf2f(ushort_t h){ return __uint_as_float(((unsigned)h) << 16); }

__device__ __forceinline__ float norm_draw(unsigned sk0, unsigned sk1, unsigned g, unsigned e){
  unsigned gk0, gk1, b0, b1;
  tf2x32(sk0, sk1, 0u, g, gk0, gk1);
  tf2x32(gk0, gk1, 0u, e, b0, b1);
  unsigned bits = b0 ^ b1;
  float u01 = bits_to_u01(bits);
  const float LO = __uint_as_float(0xBF7FFFFFu);
  float u = u01 * 2.0f + LO;
  u = fmaxf(LO, u);
  return 1.41421356237f * erfinv_f(u);
}

// ---------------- geometry ----------------
constexpr int BT = 64;      // batch rows per block
constexpr int P0 = 168;     // H0 LDS pitch: [h0 128 | x0 x1 1 | 0-pad]
constexpr int P1 = 296;     // H1 LDS pitch: [h1 128 | hd/x 128 | 1 | 0-pad]  (K window 288)

// ---------------- fused prep: mask + weights + sampling + KL ----------------
__global__ void prep_all(
    const float* __restrict__ wih0,  const float* __restrict__ whh0,
    const float* __restrict__ bih0,  const float* __restrict__ bhh0,
    const float* __restrict__ wih1,  const float* __restrict__ whh1,
    const float* __restrict__ bih1,  const float* __restrict__ bhh1,
    const float* __restrict__ din_wmu, const float* __restrict__ din_wrho,
    const float* __restrict__ din_bmu, const float* __restrict__ din_brho,
    const float* __restrict__ dhid_wmu, const float* __restrict__ dhid_wrho,
    const float* __restrict__ dhid_bmu, const float* __restrict__ dhid_brho,
    const float* __restrict__ out_wmu, const float* __restrict__ out_wrho,
    const float* __restrict__ out_bmu, const float* __restrict__ out_brho,
    ushort_t* __restrict__ whh0e, ushort_t* __restrict__ w1e,
    ushort_t* __restrict__ dwhide, float* __restrict__ dwout, float* __restrict__ dbout,
    unsigned* __restrict__ maskT, float* __restrict__ out){
  const int blk = blockIdx.x, tid = threadIdx.x;

  if (blk < 4096){
    // dropout mask, transposed: word = t*131072 + h*1024 + (b>>5), bit = b&31
    unsigned w = blk * 256u + tid;
    unsigned t = w >> 17, h = (w >> 10) & 127u, bw = w & 1023u;
    unsigned word = 0;
    #pragma unroll 4
    for (int i = 0; i < 32; ++i){
      unsigned ctr = (bw * 32u + i) * 1024u + t * 128u + h;
      unsigned o0, o1;
      tf2x32(0u, 1u, 0u, ctr, o0, o1);
      float u = bits_to_u01(o0 ^ o1);
      word |= (u < 0.9f ? 1u : 0u) << i;
    }
    maskT[w] = word;
  } else if (blk < 4992){
    int idx = (blk - 4096) * 256 + tid;  // < 229376 exactly
    if (idx < 81920){
      // whh0e: [whh0 | wih0(2) | bias | 0...], K=160
      int row = idx / 160, col = idx - row * 160;
      float v;
      if (col < 128)       v = whh0[row * 128 + col];
      else if (col == 128) v = wih0[row * 2];
      else if (col == 129) v = wih0[row * 2 + 1];
      else if (col == 130) v = bih0[row] + bhh0[row];
      else                 v = 0.0f;
      whh0e[idx] = f2bf(v);
    } else {
      // w1e: [whh1(128) | wih1(128) | bias1 | 0...], K=288
      int j = idx - 81920;   // < 147456
      int row = j / 288, col = j - row * 288;
      float v;
      if (col < 128)       v = whh1[row * 128 + col];
      else if (col < 256)  v = wih1[row * 128 + (col - 128)];
      else if (col == 256) v = bih1[row] + bhh1[row];
      else                 v = 0.0f;
      w1e[j] = f2bf(v);
    }
  } else if (blk < 8857){
    // decoder sampled weights (key(2), partitionable threefry)
    int idx = (blk - 4992) * 256 + tid;
    if (idx >= 12 * 82436) return;
    int s = idx / 82436, r = idx - s * 82436;
    unsigned sk0, sk1;
    tf2x32(0u, 2u, 0u, (unsigned)s, sk0, sk1);
    if (r < 81920){
      int row = r / 160, col = r - row * 160;
      float v;
      if (col < 128){
        unsigned e = (unsigned)(row * 128 + col);
        v = dhid_wmu[e] + log1pf(expf(dhid_wrho[e])) * norm_draw(sk0, sk1, 2u, e);
      } else if (col == 128){
        unsigned e = (unsigned)(row * 2);
        v = din_wmu[e] + log1pf(expf(din_wrho[e])) * norm_draw(sk0, sk1, 0u, e);
      } else if (col == 129){
        unsigned e = (unsigned)(row * 2 + 1);
        v = din_wmu[e] + log1pf(expf(din_wrho[e])) * norm_draw(sk0, sk1, 0u, e);
      } else if (col == 130){
        unsigned e = (unsigned)row;
        float v1 = din_bmu[e]  + log1pf(expf(din_brho[e]))  * norm_draw(sk0, sk1, 1u, e);
        float v2 = dhid_bmu[e] + log1pf(expf(dhid_brho[e])) * norm_draw(sk0, sk1, 3u, e);
        v = v1 + v2;
      } else v = 0.0f;
      dwhide[s * 81920 + r] = f2bf(v);
    } else if (r < 82432){
      unsigned e = (unsigned)(r - 81920);
      dwout[s * 512 + e] = out_wmu[e] + log1pf(expf(out_wrho[e])) * norm_draw(sk0, sk1, 4u, e);
    } else {
      unsigned e = (unsigned)(r - 82432);
      dbout[s * 4 + e] = out_bmu[e] + log1pf(expf(out_brho[e])) * norm_draw(sk0, sk1, 5u, e);
    }
  } else {
    // KL
    __shared__ float red[256];
    float s = 0.f;
    auto term = [](float mu, float rho){
      float stdv = log1pf(expf(rho));
      return logf(0.1f / stdv) + (stdv * stdv + mu * mu) * 50.0f - 0.5f;
    };
    for (int i = tid; i < 1024;  i += 256) s += term(din_wmu[i], din_wrho[i]);
    for (int i = tid; i < 512;   i += 256) s += term(din_bmu[i], din_brho[i]);
    for (int i = tid; i < 65536; i += 256) s += term(dhid_wmu[i], dhid_wrho[i]);
    for (int i = tid; i < 512;   i += 256) s += term(dhid_bmu[i], dhid_brho[i]);
    for (int i = tid; i < 512;   i += 256) s += term(out_wmu[i], out_wrho[i]);
    if (tid < 4) s += term(out_bmu[tid], out_brho[tid]);
    red[tid] = s;
    __syncthreads();
    for (int off = 128; off > 0; off >>= 1){
      if (tid < off) red[tid] += red[tid + off];
      __syncthreads();
    }
    if (tid == 0) out[1572864] = red[0];
  }
}

// ---------------- activation ----------------
__device__ __forceinline__ float lstm_elem(float gi, float gf, float gg, float go, float& c){
  float sf = __builtin_amdgcn_rcpf(1.0f + __expf(-gf));
  float Ei = __expf(-gi);
  float Eg = __expf(2.0f * gg);
  float itanh = (Eg - 1.0f) * __builtin_amdgcn_rcpf((1.0f + Ei) * (Eg + 1.0f));
  float cn = sf * c + itanh;
  c = cn;
  float Eo = __expf(-go);
  float Ec = __expf(2.0f * cn);
  return (Ec - 1.0f) * __builtin_amdgcn_rcpf((1.0f + Eo) * (Ec + 1.0f));
}

__device__ __forceinline__ float cp_lo(unsigned w){ return __uint_as_float(w << 16); }
__device__ __forceinline__ float cp_hi(unsigned w){ return __uint_as_float(w & 0xFFFF0000u); }
__device__ __forceinline__ unsigned cp_pack(float lo, float hi){
  return (__float_as_uint(hi) & 0xFFFF0000u) | (__float_as_uint(lo) >> 16);
}

// ---------------- burst B-fragment load ----------------
// row = 16*wv + lx; per-lane k elems = kofs + 32*ki + 8*lg
template<int NKI, int WROW>
__device__ __forceinline__ void load_B(const ushort_t* __restrict__ W, int row, int lg, int kofs,
                                       bf16x8 (&B)[4][NKI]){
  const ushort_t* wp = W + row * WROW + kofs + 8 * lg;
  #pragma unroll
  for (int g = 0; g < 4; ++g)
    #pragma unroll
    for (int ki = 0; ki < NKI; ++ki)
      B[g][ki] = *(const bf16x8*)(wp + 128 * g * WROW + 32 * ki);
}

// ---------------- GEMM with preloaded B frags ----------------
template<int NKI, int P>
__device__ __forceinline__ void gemm_pre(const ushort_t* __restrict__ H, int lx, int lg,
                                         const bf16x8 (&B)[4][NKI], f32x4 (&acc)[4][4]){
  #pragma unroll
  for (int ki = 0; ki < NKI; ++ki){
    bf16x8 a[4];
    #pragma unroll
    for (int m = 0; m < 4; ++m)
      a[m] = *(const bf16x8*)(H + (16 * m + lx) * P + 32 * ki + 8 * lg);
    #pragma unroll
    for (int g = 0; g < 4; ++g)
      #pragma unroll
      for (int m = 0; m < 4; ++m)
        acc[g][m] = __builtin_amdgcn_mfma_f32_16x16x32_bf16(a[m], B[g][ki], acc[g][m], 0, 0, 0);
  }
}

#define ZERO_ACC(acc) { _Pragma("unroll") for (int g_=0;g_<4;++g_) _Pragma("unroll") for (int m_=0;m_<4;++m_) acc[g_][m_] = (f32x4){0.f,0.f,0.f,0.f}; }

// ---------------- decoder step ----------------
__device__ __forceinline__ void dec_step(
    int s, ushort_t* __restrict__ H1, int tid, int lx, int lg, int hj, int b0,
    bf16x8 (&BC)[4][3], bf16x8 (&BN)[4][3], bf16x8 (&BT2)[4][2],
    unsigned (&c1p)[8], const ushort_t* __restrict__ dw_cur, const ushort_t* __restrict__ dw_next,
    const float* __restrict__ dwout, const float* __restrict__ dbout, float* __restrict__ out){
  const int row = hj;
  f32x4 acc[4][4];
  ZERO_ACC(acc);
  gemm_pre<3, P1>(H1, lx, lg, BC, acc);
  load_B<2, 160>(dw_cur, row, lg, 96, BT2);
  gemm_pre<2, P1>(H1 + 96, lx, lg, BT2, acc);
  __syncthreads();
  // pointwise
  #pragma unroll
  for (int m = 0; m < 4; ++m){
    #pragma unroll
    for (int ep = 0; ep < 2; ++ep){
      unsigned cw = c1p[m * 2 + ep];
      float cv0 = cp_lo(cw), cv1 = cp_hi(cw);
      int e0 = 2 * ep, r0 = 16 * m + 4 * lg + e0;
      float h0v = lstm_elem(acc[0][m][e0], acc[1][m][e0], acc[2][m][e0], acc[3][m][e0], cv0);
      float h1v = lstm_elem(acc[0][m][e0+1], acc[1][m][e0+1], acc[2][m][e0+1], acc[3][m][e0+1], cv1);
      c1p[m * 2 + ep] = cp_pack(cv0, cv1);
      H1[r0 * P1 + hj] = f2bf(h0v);
      H1[(r0 + 1) * P1 + hj] = f2bf(h1v);
    }
  }
  load_B<3, 160>(dw_next, row, lg, 0, BN);  // prefetch next step, hidden here
  __syncthreads();
  // out-head: all 512 threads, split-K, shuffle combine
  {
    int o = tid & 3, half = (tid >> 2) & 1, r = tid >> 3;
    const float* wo = dwout + s * 512 + o * 128 + half * 64;
    const ushort_t* hrow = H1 + r * P1 + half * 64;
    float sum = half ? 0.0f : dbout[s * 4 + o];
    #pragma unroll
    for (int k = 0; k < 64; k += 8){
      bf16x8 hv = *(const bf16x8*)(hrow + k);
      f32x4 wa = *(const f32x4*)(wo + k);
      f32x4 wb = *(const f32x4*)(wo + k + 4);
      sum += bf2f((ushort_t)hv[0]) * wa[0] + bf2f((ushort_t)hv[1]) * wa[1]
           + bf2f((ushort_t)hv[2]) * wa[2] + bf2f((ushort_t)hv[3]) * wa[3]
           + bf2f((ushort_t)hv[4]) * wb[0] + bf2f((ushort_t)hv[5]) * wb[1]
           + bf2f((ushort_t)hv[6]) * wb[2] + bf2f((ushort_t)hv[7]) * wb[3];
    }
    sum += __shfl_xor(sum, 4);
    if (half == 0){
      int gb = b0 + r;
      if (o < 2){
        out[gb * 24 + s * 2 + o] = sum;
        H1[r * P1 + 128 + o] = f2bf(sum);   // mu feedback
      } else {
        out[786432 + gb * 24 + s * 2 + (o - 2)] = fminf(fmaxf(sum, -4.0f), 2.0f);
      }
    }
  }
  __syncthreads();
}

// ---------------- main fused kernel: 512 thr (8 waves), BT=64, grid 512 ----------------
__global__ __launch_bounds__(512, 2) void lstm_main(
    const float* __restrict__ obs,
    const ushort_t* __restrict__ whh0e,   // [512][160]
    const ushort_t* __restrict__ w1e,     // [512][288]
    const ushort_t* __restrict__ dwhide,  // [12][512][160]
    const float* __restrict__ dwout,      // [12][4][128]
    const float* __restrict__ dbout,      // [12][4]
    const unsigned* __restrict__ maskT,   // [8][128][1024]
    float* __restrict__ out){
  __shared__ __align__(16) ushort_t H0s[BT * P0];   // 21504 B
  __shared__ __align__(16) ushort_t H1s[BT * P1];   // 37888 B
  __shared__ float OBSs[BT * 16];                   // 4096 B

  const int tid = threadIdx.x;
  const int wv = tid >> 6;
  const int l  = tid & 63;
  const int lx = l & 15;
  const int lg = l >> 4;
  const int b0 = blockIdx.x * BT;
  const int hj = 16 * wv + lx;

  bf16x8 B0[4][5];   // layer-0 W (K=160)
  bf16x8 BwA[4][3], BwB[4][3];

  load_B<5, 160>(whh0e, hj, lg, 0, B0);   // prime layer-0 W

  for (int i = tid; i < BT * 16; i += 512) OBSs[i] = obs[b0 * 16 + i];
  {
    uint_t* p0 = (uint_t*)H0s;
    for (int i = tid; i < BT * P0 / 2; i += 512) p0[i] = 0;
    uint_t* p1 = (uint_t*)H1s;
    for (int i = tid; i < BT * P1 / 2; i += 512) p1[i] = 0;
  }
  __syncthreads();
  if (tid < 64){
    H0s[tid * P0 + 130] = (ushort_t)0x3F80;  // 1.0 (bias col)
    H1s[tid * P1 + 256] = (ushort_t)0x3F80;  // 1.0 (bias col, layer-1)
  }
  if (tid < 128){
    int r = tid >> 1, c = tid & 1;
    H0s[r * P0 + 128 + c] = f2bf(OBSs[r * 16 + c]);   // x_0
  }
  unsigned c0p[8], c1p[8];
  #pragma unroll
  for (int i = 0; i < 8; ++i){ c0p[i] = 0; c1p[i] = 0; }
  __syncthreads();

  // ================= encoder: 8 steps =================
  for (int t = 0; t < 8; ++t){
    f32x4 acc[4][4];
    // ---- layer 0: [h0 | x | 1] @ whh0e^T ----
    ZERO_ACC(acc);
    gemm_pre<5, P0>(H0s, lx, lg, B0, acc);
    __syncthreads();
    // ---- pointwise 0 (+ dropout to H1s cols 128..255); load W1e chunk0 here ----
    load_B<3, 288>(w1e, hj, lg, 0, BwA);
    {
      uint2 mk = *(const uint2*)(maskT + (unsigned)t * 131072u + (unsigned)hj * 1024u + (unsigned)(blockIdx.x * 2));
      #pragma unroll
      for (int m = 0; m < 4; ++m){
        unsigned mbits = (m & 2) ? mk.y : mk.x;
        #pragma unroll
        for (int ep = 0; ep < 2; ++ep){
          unsigned cw = c0p[m * 2 + ep];
          float cv0 = cp_lo(cw), cv1 = cp_hi(cw);
          int e0 = 2 * ep, r0 = 16 * m + 4 * lg + e0;
          float h0v = lstm_elem(acc[0][m][e0], acc[1][m][e0], acc[2][m][e0], acc[3][m][e0], cv0);
          float h1v = lstm_elem(acc[0][m][e0+1], acc[1][m][e0+1], acc[2][m][e0+1], acc[3][m][e0+1], cv1);
          c0p[m * 2 + ep] = cp_pack(cv0, cv1);
          H0s[r0 * P0 + hj] = f2bf(h0v);
          H0s[(r0 + 1) * P0 + hj] = f2bf(h1v);
          unsigned k0 = (mbits >> (r0 & 31)) & 1u;
          unsigned k1 = (mbits >> ((r0 + 1) & 31)) & 1u;
          H1s[r0 * P1 + 128 + hj] = k0 ? f2bf(h0v * (1.0f / 0.9f)) : (ushort_t)0;
          H1s[(r0 + 1) * P1 + 128 + hj] = k1 ? f2bf(h1v * (1.0f / 0.9f)) : (ushort_t)0;
        }
      }
    }
    __syncthreads();
    // ---- layer 1: [h1 | hd | 1] @ w1e^T, K=288 in 3 ping-pong chunks ----
    ZERO_ACC(acc);
    gemm_pre<3, P1>(H1s, lx, lg, BwA, acc);
    load_B<3, 288>(w1e, hj, lg, 96, BwB);
    gemm_pre<3, P1>(H1s + 96, lx, lg, BwB, acc);
    load_B<3, 288>(w1e, hj, lg, 192, BwA);
    gemm_pre<3, P1>(H1s + 192, lx, lg, BwA, acc);
    __syncthreads();
    // ---- pointwise 1; reload layer-0 W for next t; stage x_{t+1} ----
    #pragma unroll
    for (int m = 0; m < 4; ++m){
      #pragma unroll
      for (int ep = 0; ep < 2; ++ep){
        unsigned cw = c1p[m * 2 + ep];
        float cv0 = cp_lo(cw), cv1 = cp_hi(cw);
        int e0 = 2 * ep, r0 = 16 * m + 4 * lg + e0;
        float h0v = lstm_elem(acc[0][m][e0], acc[1][m][e0], acc[2][m][e0], acc[3][m][e0], cv0);
        float h1v = lstm_elem(acc[0][m][e0+1], acc[1][m][e0+1], acc[2][m][e0+1], acc[3][m][e0+1], cv1);
        c1p[m * 2 + ep] = cp_pack(cv0, cv1);
        H1s[r0 * P1 + hj] = f2bf(h0v);
        H1s[(r0 + 1) * P1 + hj] = f2bf(h1v);
      }
    }
    load_B<5, 160>(whh0e, hj, lg, 0, B0);
    if (t < 7 && tid < 128){
      int r = tid >> 1, c = tid & 1;
      H0s[r * P0 + 128 + c] = f2bf(OBSs[r * 16 + 2 * (t + 1) + c]);
    }
    __syncthreads();
  }

  // ================= transition to decoder =================
  bf16x8 BdA[4][3], BdB[4][3], BdT[4][2];
  load_B<3, 160>(dwhide, hj, lg, 0, BdA);   // step-0 W prefetch
  for (int i = tid; i < BT * 32; i += 512){ // clear cols 128..159 (held hd)
    int r = i >> 5, c = i & 31;
    H1s[r * P1 + 128 + c] = 0;
  }
  __syncthreads();
  if (tid < 128){
    int r = tid >> 1, c = tid & 1;
    H1s[r * P1 + 128 + c] = f2bf(OBSs[r * 16 + 14 + c]);  // x = obs[:,7,:]
  }
  if (tid < 64) H1s[tid * P1 + 130] = (ushort_t)0x3F80;   // bias col
  __syncthreads();

  // ================= decoder: 12 steps (2-step ping-pong) =================
  for (int s = 0; s < 12; s += 2){
    const ushort_t* dw0 = dwhide + s * 81920;
    const ushort_t* dw1 = dwhide + (s + 1) * 81920;
    const ushort_t* dw2 = dwhide + (s + 2 < 12 ? s + 2 : 11) * 81920;
    dec_step(s,     H1s, tid, lx, lg, hj, b0, BdA, BdB, BdT, c1p, dw0, dw1, dwout, dbout, out);
    dec_step(s + 1, H1s, tid, lx, lg, hj, b0, BdB, BdA, BdT, c1p, dw1, dw2, dwout, dbout, out);
  }
}

// ---------------- launch ----------------
extern "C" void kernel_launch(void* const* d_in, const int* in_sizes, int n_in,
                              void* d_out, int out_size, void* d_ws, size_t ws_size,
                              hipStream_t stream){
  (void)in_sizes; (void)n_in; (void)out_size; (void)ws_size;
  const float* obs   = (const float*)d_in[0];
  const float* wih0  = (const float*)d_in[1];
  const float* whh0  = (const float*)d_in[2];
  const float* bih0  = (const float*)d_in[3];
  const float* bhh0  = (const float*)d_in[4];
  const float* wih1  = (const float*)d_in[5];
  const float* whh1  = (const float*)d_in[6];
  const float* bih1  = (const float*)d_in[7];
  const float* bhh1  = (const float*)d_in[8];
  const float* din_wmu  = (const float*)d_in[9];
  const float* din_wrho = (const float*)d_in[10];
  const float* din_bmu  = (const float*)d_in[11];
  const float* din_brho = (const float*)d_in[12];
  const float* dhid_wmu  = (const float*)d_in[13];
  const float* dhid_wrho = (const float*)d_in[14];
  const float* dhid_bmu  = (const float*)d_in[15];
  const float* dhid_brho = (const float*)d_in[16];
  const float* out_wmu  = (const float*)d_in[17];
  const float* out_wrho = (const float*)d_in[18];
  const float* out_bmu  = (const float*)d_in[19];
  const float* out_brho = (const float*)d_in[20];

  char* wsb = (char*)d_ws;
  ushort_t* whh0e  = (ushort_t*)(wsb + 0);         // 163840 B
  ushort_t* w1e    = (ushort_t*)(wsb + 163840);    // 294912 B
  ushort_t* dwhide = (ushort_t*)(wsb + 458752);    // 1966080 B
  float*    dwout  = (float*)(wsb + 2424832);      // 24576 B
  float*    dbout  = (float*)(wsb + 2449408);      // 192 B
  unsigned* maskT  = (unsigned*)(wsb + 2449600);   // 4194304 B

  prep_all<<<8858, 256, 0, stream>>>(
      wih0, whh0, bih0, bhh0, wih1, whh1, bih1, bhh1,
      din_wmu, din_wrho, din_bmu, din_brho,
      dhid_wmu, dhid_wrho, dhid_bmu, dhid_brho,
      out_wmu, out_wrho, out_bmu, out_brho,
      whh0e, w1e, dwhide, dwout, dbout, maskT, (float*)d_out);

  lstm_main<<<512, 512, 0, stream>>>(obs, whh0e, w1e, dwhide, dwout, dbout,
                                     maskT, (float*)d_out);
}

// Round 4
// 958.612 us; speedup vs baseline: 1.2345x; 1.2345x over previous
//
#include <hip/hip_runtime.h>

typedef float f32x4 __attribute__((ext_vector_type(4)));
typedef float f32x2 __attribute__((ext_vector_type(2)));
typedef short bf16x8 __attribute__((ext_vector_type(8)));
typedef unsigned short ushort_t;
typedef unsigned int uint_t;

#define LOG2E  1.442695041f
#define LOG2E2 2.885390082f

// ---------------- Threefry-2x32 (20 rounds), exact JAX semantics (verified r1) ----------------
__device__ __forceinline__ unsigned rotl32(unsigned x, unsigned r){ return (x << r) | (x >> (32u - r)); }

__device__ __forceinline__ void tf2x32(unsigned k0, unsigned k1, unsigned c0, unsigned c1,
                                       unsigned &o0, unsigned &o1){
  unsigned ks2 = k0 ^ k1 ^ 0x1BD11BDAu;
  unsigned x0 = c0 + k0, x1 = c1 + k1;
#define TFR(r) { x0 += x1; x1 = rotl32(x1, r); x1 ^= x0; }
  TFR(13) TFR(15) TFR(26) TFR(6)
  x0 += k1;  x1 += ks2 + 1u;
  TFR(17) TFR(29) TFR(16) TFR(24)
  x0 += ks2; x1 += k0 + 2u;
  TFR(13) TFR(15) TFR(26) TFR(6)
  x0 += k0;  x1 += k1 + 3u;
  TFR(17) TFR(29) TFR(16) TFR(24)
  x0 += k1;  x1 += ks2 + 4u;
  TFR(13) TFR(15) TFR(26) TFR(6)
  x0 += ks2; x1 += k0 + 5u;
#undef TFR
  o0 = x0; o1 = x1;
}

__device__ __forceinline__ float bits_to_u01(unsigned bits){
  return __uint_as_float((bits >> 9) | 0x3f800000u) - 1.0f;
}

// XLA ErfInv32 (Giles polynomial) — verified r1
__device__ __forceinline__ float erfinv_f(float x){
  float w = -log1pf(-x * x);
  float p;
  if (w < 5.0f){
    w -= 2.5f;
    p = 2.81022636e-08f;
    p = 3.43273939e-07f + p * w;
    p = -3.5233877e-06f + p * w;
    p = -4.39150654e-06f + p * w;
    p = 0.00021858087f + p * w;
    p = -0.00125372503f + p * w;
    p = -0.00417768164f + p * w;
    p = 0.246640727f + p * w;
    p = 1.50140941f + p * w;
  } else {
    w = sqrtf(w) - 3.0f;
    p = -0.000200214257f;
    p = 0.000100950558f + p * w;
    p = 0.00134934322f + p * w;
    p = -0.00367342844f + p * w;
    p = 0.00573950773f + p * w;
    p = -0.0076224613f + p * w;
    p = 0.00943887047f + p * w;
    p = 1.00167406f + p * w;
    p = 2.83297682f + p * w;
  }
  return p * x;
}

__device__ __forceinline__ ushort_t f2bf(float f){
  unsigned u = __float_as_uint(f);
  unsigned r = u + 0x7fffu + ((u >> 16) & 1u);
  return (ushort_t)(r >> 16);
}

__device__ __forceinline__ float norm_draw(unsigned sk0, unsigned sk1, unsigned g, unsigned e){
  unsigned gk0, gk1, b0, b1;
  tf2x32(sk0, sk1, 0u, g, gk0, gk1);
  tf2x32(gk0, gk1, 0u, e, b0, b1);
  unsigned bits = b0 ^ b1;
  float u01 = bits_to_u01(bits);
  const float LO = __uint_as_float(0xBF7FFFFFu);
  float u = u01 * 2.0f + LO;
  u = fmaxf(LO, u);
  return 1.41421356237f * erfinv_f(u);
}

__device__ __forceinline__ float softplus_f(float r){ return log1pf(expf(r)); }
__device__ __forceinline__ float gscale(int gate){ return gate == 2 ? LOG2E2 : LOG2E; }

// ---------------- fast device math for main kernel ----------------
__device__ __forceinline__ float fexp2(float x){
  float r;
  asm("v_exp_f32 %0, %1" : "=v"(r) : "v"(x));
  return r;
}
__device__ __forceinline__ float frcp(float x){ return __builtin_amdgcn_rcpf(x); }

// gates are PRE-SCALED: i,f,o by log2e; g by 2*log2e (folded into weights in prep)
__device__ __forceinline__ float lstm_act(float gi, float gf, float gg, float go, float& c){
  float Ef = fexp2(gf);
  float sf = Ef * frcp(1.0f + Ef);
  float EiN = fexp2(-gi);
  float Eg  = fexp2(gg);
  float cn = sf * c + (Eg - 1.0f) * frcp((1.0f + EiN) * (Eg + 1.0f));
  c = cn;
  float EoN = fexp2(-go);
  float Ec  = fexp2(cn * LOG2E2);
  return (Ec - 1.0f) * frcp((1.0f + EoN) * (Ec + 1.0f));
}

__device__ __forceinline__ float cp_lo(unsigned w){ return __uint_as_float(w << 16); }
__device__ __forceinline__ float cp_hi(unsigned w){ return __uint_as_float(w & 0xFFFF0000u); }
__device__ __forceinline__ unsigned cp_pack(float lo, float hi){
  return (__float_as_uint(hi) & 0xFFFF0000u) | (__float_as_uint(lo) >> 16);
}

// ---------------- geometry ----------------
constexpr int P0 = 136;   // H0 pitch (elems): h0[128] + pad
constexpr int P1 = 264;   // H1 pitch: h1[128] | hd[128] | pad

// ---------------- fused prep ----------------
__global__ void prep_all(
    const float* __restrict__ wih0,  const float* __restrict__ whh0,
    const float* __restrict__ bih0,  const float* __restrict__ bhh0,
    const float* __restrict__ wih1,  const float* __restrict__ whh1,
    const float* __restrict__ bih1,  const float* __restrict__ bhh1,
    const float* __restrict__ din_wmu, const float* __restrict__ din_wrho,
    const float* __restrict__ din_bmu, const float* __restrict__ din_brho,
    const float* __restrict__ dhid_wmu, const float* __restrict__ dhid_wrho,
    const float* __restrict__ dhid_bmu, const float* __restrict__ dhid_brho,
    const float* __restrict__ out_wmu, const float* __restrict__ out_wrho,
    const float* __restrict__ out_bmu, const float* __restrict__ out_brho,
    ushort_t* __restrict__ whh0b, ushort_t* __restrict__ w1e,
    float* __restrict__ wx0s, float* __restrict__ b0s, float* __restrict__ b1s,
    ushort_t* __restrict__ dwhidb, float* __restrict__ dwinb, float* __restrict__ dbsum,
    ushort_t* __restrict__ dwoutb, float* __restrict__ dbout,
    unsigned* __restrict__ maskT, float* __restrict__ out){
  const int blk = blockIdx.x, tid = threadIdx.x;

  if (blk < 4096){
    // dropout mask, transposed: word = t*131072 + h*1024 + (b>>5), bit = b&31 (verified r1)
    unsigned w = blk * 256u + tid;
    unsigned t = w >> 17, h = (w >> 10) & 127u, bw = w & 1023u;
    unsigned word = 0;
    #pragma unroll 4
    for (int i = 0; i < 32; ++i){
      unsigned ctr = (bw * 32u + i) * 1024u + t * 128u + h;
      unsigned o0, o1;
      tf2x32(0u, 1u, 0u, ctr, o0, o1);
      float u = bits_to_u01(o0 ^ o1);
      word |= (u < 0.9f ? 1u : 0u) << i;
    }
    maskT[w] = word;
  } else if (blk < 4872){
    int idx = (blk - 4096) * 256 + tid;   // < 198656 exact
    if (idx < 65536){
      int row = idx >> 7;
      whh0b[idx] = f2bf(whh0[idx] * gscale(row >> 7));
    } else if (idx < 196608){
      int j = idx - 65536;
      int row = j >> 8, col = j & 255;
      float v = col < 128 ? whh1[row * 128 + col] : wih1[row * 128 + (col - 128)];
      w1e[j] = f2bf(v * gscale(row >> 7));
    } else if (idx < 197632){
      int j = idx - 196608;   // < 1024, row = j>>1
      wx0s[j] = wih0[j] * gscale(j >> 8);
    } else if (idx < 198144){
      int j = idx - 197632;
      b0s[j] = (bih0[j] + bhh0[j]) * gscale(j >> 7);
    } else {
      int j = idx - 198144;
      b1s[j] = (bih1[j] + bhh1[j]) * gscale(j >> 7);
    }
  } else if (blk < 8113){
    int idx = (blk - 4872) * 256 + tid;
    if (idx < 829488){
      int s = idx / 69124, r = idx - s * 69124;
      unsigned sk0, sk1;
      tf2x32(0u, 2u, 0u, (unsigned)s, sk0, sk1);   // split(key(2), 12)
      if (r < 65536){
        int row = r >> 7;
        float v = dhid_wmu[r] + softplus_f(dhid_wrho[r]) * norm_draw(sk0, sk1, 2u, (unsigned)r);
        dwhidb[s * 65536 + r] = f2bf(v * gscale(row >> 7));
      } else if (r < 66560){
        int j = r - 65536;   // row = j>>1
        float v = din_wmu[j] + softplus_f(din_wrho[j]) * norm_draw(sk0, sk1, 0u, (unsigned)j);
        dwinb[s * 1024 + j] = v * gscale(j >> 8);
      } else if (r < 67072){
        int j = r - 66560;
        float v1 = din_bmu[j]  + softplus_f(din_brho[j])  * norm_draw(sk0, sk1, 1u, (unsigned)j);
        float v2 = dhid_bmu[j] + softplus_f(dhid_brho[j]) * norm_draw(sk0, sk1, 3u, (unsigned)j);
        dbsum[s * 512 + j] = (v1 + v2) * gscale(j >> 7);
      } else if (r < 69120){
        int j = r - 67072;   // n = j>>7, k = j&127, e = j
        ushort_t v = 0;
        if (j < 512)
          v = f2bf(out_wmu[j] + softplus_f(out_wrho[j]) * norm_draw(sk0, sk1, 4u, (unsigned)j));
        dwoutb[s * 2048 + j] = v;
      } else {
        int j = r - 69120;
        dbout[s * 4 + j] = out_bmu[j] + softplus_f(out_brho[j]) * norm_draw(sk0, sk1, 5u, (unsigned)j);
      }
    }
  } else {
    // KL: 267 blocks, atomicAdd into out[1572864] (zeroed by hipMemsetAsync)
    int idx = (blk - 8113) * 256 + tid;
    float s = 0.f;
    if (idx < 68100){
      float mu, rho;
      if (idx < 1024){ mu = din_wmu[idx]; rho = din_wrho[idx]; }
      else if (idx < 1536){ mu = din_bmu[idx-1024]; rho = din_brho[idx-1024]; }
      else if (idx < 67072){ mu = dhid_wmu[idx-1536]; rho = dhid_wrho[idx-1536]; }
      else if (idx < 67584){ mu = dhid_bmu[idx-67072]; rho = dhid_brho[idx-67072]; }
      else if (idx < 68096){ mu = out_wmu[idx-67584]; rho = out_wrho[idx-67584]; }
      else { mu = out_bmu[idx-68096]; rho = out_brho[idx-68096]; }
      float stdv = softplus_f(rho);
      s = logf(0.1f / stdv) + (stdv * stdv + mu * mu) * 50.0f - 0.5f;
    }
    __shared__ float red[256];
    red[tid] = s;
    __syncthreads();
    for (int off = 128; off > 0; off >>= 1){
      if (tid < off) red[tid] += red[tid + off];
      __syncthreads();
    }
    if (tid == 0) atomicAdd(out + 1572864, red[0]);
  }
}

// ---------------- GEMM helpers ----------------
template<int NKI>
__device__ __forceinline__ void loadBfull(const ushort_t* __restrict__ W, int WROW,
                                          int hj, int lg, bf16x8 (&B)[4][NKI]){
  const ushort_t* wp = W + (size_t)hj * WROW + 8 * lg;
  #pragma unroll
  for (int g = 0; g < 4; ++g)
    #pragma unroll
    for (int ki = 0; ki < NKI; ++ki)
      B[g][ki] = *(const bf16x8*)(wp + (size_t)(128 * g) * WROW + 32 * ki);
}

#define ZACC(acc) { _Pragma("unroll") for (int g_=0;g_<4;++g_) _Pragma("unroll") for (int m_=0;m_<4;++m_) acc[g_][m_] = (f32x4){0.f,0.f,0.f,0.f}; }

template<int H, int NKI, int P>
__device__ __forceinline__ void gemm_half(const ushort_t* __restrict__ Hl, int lx, int lg,
                                          const bf16x8 (&B)[4][NKI], f32x4 (&acc)[4][4]){
  ZACC(acc);
  #pragma unroll
  for (int m = 0; m < 4; ++m){
    const ushort_t* hp = Hl + (64 * H + 16 * m + lx) * P + 8 * lg;
    bf16x8 a[NKI];
    #pragma unroll
    for (int ki = 0; ki < NKI; ++ki) a[ki] = *(const bf16x8*)(hp + 32 * ki);
    #pragma unroll
    for (int ki = 0; ki < NKI; ++ki)
      #pragma unroll
      for (int g = 0; g < 4; ++g)
        acc[g][m] = __builtin_amdgcn_mfma_f32_16x16x32_bf16(a[ki], B[g][ki], acc[g][m], 0, 0, 0);
  }
}

__device__ __forceinline__ void loadBchunk(const ushort_t* __restrict__ w1e, int hj, int lg,
                                           int kc, bf16x8 (&B)[4][2]){
  const ushort_t* wp = w1e + (size_t)hj * 256 + 64 * kc + 8 * lg;
  #pragma unroll
  for (int g = 0; g < 4; ++g){
    B[g][0] = *(const bf16x8*)(wp + (size_t)(128 * g) * 256);
    B[g][1] = *(const bf16x8*)(wp + (size_t)(128 * g) * 256 + 32);
  }
}

template<int H>
__device__ __forceinline__ void gemm1_half(const ushort_t* __restrict__ H1, int lx, int lg, int hj,
                                           const ushort_t* __restrict__ w1e,
                                           bf16x8 (&Bp)[4][2], bf16x8 (&Bq)[4][2], f32x4 (&acc)[4][4]){
  ZACC(acc);
  #pragma unroll
  for (int kc = 0; kc < 4; ++kc){
    bf16x8 (&cur)[4][2] = (kc & 1) ? Bq : Bp;
    bf16x8 (&nxt)[4][2] = (kc & 1) ? Bp : Bq;
    if (kc < 3) loadBchunk(w1e, hj, lg, kc + 1, nxt);
    #pragma unroll
    for (int m = 0; m < 4; ++m){
      const ushort_t* hp = H1 + (64 * H + 16 * m + lx) * P1 + 64 * kc + 8 * lg;
      bf16x8 a0 = *(const bf16x8*)(hp);
      bf16x8 a1 = *(const bf16x8*)(hp + 32);
      #pragma unroll
      for (int g = 0; g < 4; ++g)
        acc[g][m] = __builtin_amdgcn_mfma_f32_16x16x32_bf16(a0, cur[g][0], acc[g][m], 0, 0, 0);
      #pragma unroll
      for (int g = 0; g < 4; ++g)
        acc[g][m] = __builtin_amdgcn_mfma_f32_16x16x32_bf16(a1, cur[g][1], acc[g][m], 0, 0, 0);
    }
  }
}

// ---------------- pointwise halves ----------------
template<int H>
__device__ __forceinline__ void pw0_half(int t, f32x4 (&acc)[4][4], unsigned* c0p,
    const float (&bv)[4], const float (&wav)[4], const float (&wbv)[4], uint4 mk,
    ushort_t* __restrict__ H0, ushort_t* __restrict__ H1, const float* __restrict__ OBSs,
    int hj, int lg){
  #pragma unroll
  for (int m = 0; m < 4; ++m){
    unsigned cwA = c0p[H*8 + m*2], cwB = c0p[H*8 + m*2 + 1];
    float cf0 = cp_lo(cwA), cf1 = cp_hi(cwA), cf2 = cp_lo(cwB), cf3 = cp_hi(cwB);
    const int wsel = H*2 + (m >> 1);
    unsigned mkw = wsel == 0 ? mk.x : wsel == 1 ? mk.y : wsel == 2 ? mk.z : mk.w;
    #pragma unroll
    for (int e = 0; e < 4; ++e){
      float& cf = e == 0 ? cf0 : e == 1 ? cf1 : e == 2 ? cf2 : cf3;
      int row = 64*H + 16*m + 4*lg + e;
      f32x2 xv = *(const f32x2*)(OBSs + row * 16 + 2 * t);
      float gi = acc[0][m][e] + bv[0] + xv.x * wav[0] + xv.y * wbv[0];
      float gf = acc[1][m][e] + bv[1] + xv.x * wav[1] + xv.y * wbv[1];
      float gg = acc[2][m][e] + bv[2] + xv.x * wav[2] + xv.y * wbv[2];
      float go = acc[3][m][e] + bv[3] + xv.x * wav[3] + xv.y * wbv[3];
      float hv = lstm_act(gi, gf, gg, go, cf);
      H0[row * P0 + hj] = f2bf(hv);
      unsigned keep = (mkw >> (((m & 1) << 4) + 4 * lg + e)) & 1u;
      H1[row * P1 + 128 + hj] = keep ? f2bf(hv * (1.0f / 0.9f)) : (ushort_t)0;
    }
    c0p[H*8 + m*2]     = cp_pack(cf0, cf1);
    c0p[H*8 + m*2 + 1] = cp_pack(cf2, cf3);
  }
}

template<int H>
__device__ __forceinline__ void pw1_half(f32x4 (&acc)[4][4], unsigned* c1p,
    const float (&bv)[4], ushort_t* __restrict__ H1, int hj, int lg){
  #pragma unroll
  for (int m = 0; m < 4; ++m){
    unsigned cwA = c1p[H*8 + m*2], cwB = c1p[H*8 + m*2 + 1];
    float cf0 = cp_lo(cwA), cf1 = cp_hi(cwA), cf2 = cp_lo(cwB), cf3 = cp_hi(cwB);
    #pragma unroll
    for (int e = 0; e < 4; ++e){
      float& cf = e == 0 ? cf0 : e == 1 ? cf1 : e == 2 ? cf2 : cf3;
      int row = 64*H + 16*m + 4*lg + e;
      float gi = acc[0][m][e] + bv[0];
      float gf = acc[1][m][e] + bv[1];
      float gg = acc[2][m][e] + bv[2];
      float go = acc[3][m][e] + bv[3];
      float hv = lstm_act(gi, gf, gg, go, cf);
      H1[row * P1 + hj] = f2bf(hv);
    }
    c1p[H*8 + m*2]     = cp_pack(cf0, cf1);
    c1p[H*8 + m*2 + 1] = cp_pack(cf2, cf3);
  }
}

template<int H>
__device__ __forceinline__ void pwd_half(f32x4 (&acc)[4][4], unsigned* c1p,
    const float (&bv)[4], const float (&wav)[4], const float (&wbv)[4],
    ushort_t* __restrict__ H1, const float* __restrict__ XDs, int hj, int lg){
  #pragma unroll
  for (int m = 0; m < 4; ++m){
    unsigned cwA = c1p[H*8 + m*2], cwB = c1p[H*8 + m*2 + 1];
    float cf0 = cp_lo(cwA), cf1 = cp_hi(cwA), cf2 = cp_lo(cwB), cf3 = cp_hi(cwB);
    #pragma unroll
    for (int e = 0; e < 4; ++e){
      float& cf = e == 0 ? cf0 : e == 1 ? cf1 : e == 2 ? cf2 : cf3;
      int row = 64*H + 16*m + 4*lg + e;
      f32x2 xv = *(const f32x2*)(XDs + 2 * row);
      float gi = acc[0][m][e] + bv[0] + xv.x * wav[0] + xv.y * wbv[0];
      float gf = acc[1][m][e] + bv[1] + xv.x * wav[1] + xv.y * wbv[1];
      float gg = acc[2][m][e] + bv[2] + xv.x * wav[2] + xv.y * wbv[2];
      float go = acc[3][m][e] + bv[3] + xv.x * wav[3] + xv.y * wbv[3];
      float hv = lstm_act(gi, gf, gg, go, cf);
      H1[row * P1 + hj] = f2bf(hv);
    }
    c1p[H*8 + m*2]     = cp_pack(cf0, cf1);
    c1p[H*8 + m*2 + 1] = cp_pack(cf2, cf3);
  }
}

// ---------------- decoder out-head: per-wave 16-row MFMA tile ----------------
__device__ __forceinline__ void out_head(int s, int mt, int lx, int lg, int b0,
    const ushort_t* __restrict__ H1, const ushort_t* __restrict__ dwoutb,
    const float* __restrict__ dbout, float* __restrict__ XDs, float* __restrict__ out){
  const ushort_t* wp = dwoutb + (size_t)s * 2048 + lx * 128 + 8 * lg;
  bf16x8 B0v = *(const bf16x8*)(wp);
  bf16x8 B1v = *(const bf16x8*)(wp + 32);
  bf16x8 B2v = *(const bf16x8*)(wp + 64);
  bf16x8 B3v = *(const bf16x8*)(wp + 96);
  const ushort_t* hp = H1 + (16 * mt + lx) * P1 + 8 * lg;
  f32x4 accO = {0.f, 0.f, 0.f, 0.f};
  accO = __builtin_amdgcn_mfma_f32_16x16x32_bf16(*(const bf16x8*)(hp),      B0v, accO, 0, 0, 0);
  accO = __builtin_amdgcn_mfma_f32_16x16x32_bf16(*(const bf16x8*)(hp + 32), B1v, accO, 0, 0, 0);
  accO = __builtin_amdgcn_mfma_f32_16x16x32_bf16(*(const bf16x8*)(hp + 64), B2v, accO, 0, 0, 0);
  accO = __builtin_amdgcn_mfma_f32_16x16x32_bf16(*(const bf16x8*)(hp + 96), B3v, accO, 0, 0, 0);
  if (lx < 4){
    float bo = dbout[s * 4 + lx];
    #pragma unroll
    for (int e = 0; e < 4; ++e){
      int row = 16 * mt + 4 * lg + e;
      float v = accO[e] + bo;
      int gb = b0 + row;
      if (lx < 2){
        out[gb * 24 + s * 2 + lx] = v;
        XDs[2 * row + lx] = v;             // mu feedback
      } else {
        out[786432 + gb * 24 + s * 2 + (lx - 2)] = fminf(fmaxf(v, -4.0f), 2.0f);
      }
    }
  }
}

// ---------------- main fused kernel: 512 thr (8 waves), BT=128, grid 256 (1 block/CU) ----------------
__global__ __launch_bounds__(512, 1) void lstm_main(
    const float* __restrict__ obs,
    const ushort_t* __restrict__ whh0b,   // [512][128] scaled
    const ushort_t* __restrict__ w1e,     // [512][256] scaled (whh1|wih1)
    const float* __restrict__ wx0s,       // [512][2] scaled
    const float* __restrict__ b0s,        // [512] scaled
    const float* __restrict__ b1s,        // [512] scaled
    const ushort_t* __restrict__ dwhidb,  // [12][512][128] scaled
    const float* __restrict__ dwinb,      // [12][512][2] scaled
    const float* __restrict__ dbsum,      // [12][512] scaled
    const ushort_t* __restrict__ dwoutb,  // [12][16][128] (unscaled, rows 4-15 = 0)
    const float* __restrict__ dbout,      // [12][4]
    const unsigned* __restrict__ maskT,   // [8][128][1024]
    float* __restrict__ out){
  __shared__ __align__(16) ushort_t H0s[128 * P0];   // 34816 B
  __shared__ __align__(16) ushort_t H1s[128 * P1];   // 67584 B
  __shared__ __align__(16) float OBSs[128 * 16];     // 8192 B
  __shared__ float XDs[256];                         // 1024 B

  const int tid = threadIdx.x;
  const int wv = tid >> 6, l = tid & 63, lx = l & 15, lg = l >> 4;
  const int hj = 16 * wv + lx;
  const int b0 = blockIdx.x * 128;

  // stage obs (2048 f32 = 512 f32x4)
  ((f32x4*)OBSs)[tid] = ((const f32x4*)(obs + (size_t)b0 * 16))[tid];
  {
    uint_t* p = (uint_t*)H0s;
    #pragma unroll 1
    for (int i = tid; i < 128 * P0 / 2; i += 512) p[i] = 0;
    uint_t* q = (uint_t*)H1s;
    #pragma unroll 1
    for (int i = tid; i < 128 * P1 / 2; i += 512) q[i] = 0;
  }

  float b0sv[4], wa0v[4], wb0v[4], b1sv[4];
  #pragma unroll
  for (int g = 0; g < 4; ++g){
    int j = 128 * g + hj;
    b0sv[g] = b0s[j];
    f32x2 w = *(const f32x2*)(wx0s + 2 * j);
    wa0v[g] = w.x; wb0v[g] = w.y;
    b1sv[g] = b1s[j];
  }
  unsigned c0p[16], c1p[16];
  #pragma unroll
  for (int i = 0; i < 16; ++i){ c0p[i] = 0; c1p[i] = 0; }

  f32x4 acc[4][4];
  bf16x8 Bf[4][4], Bp[4][2], Bq[4][2];

  __syncthreads();

  // ================= encoder: 8 steps, 4 phases each =================
  #pragma unroll 1
  for (int t = 0; t < 8; ++t){
    // P1: [pw1-h1(t-1) || g0-h0(t)]
    loadBfull<4>(whh0b, 128, hj, lg, Bf);
    const uint4 mk = *(const uint4*)(maskT + (size_t)t * 131072 + (size_t)hj * 1024 + blockIdx.x * 4);
    if (t > 0) pw1_half<1>(acc, c1p, b1sv, H1s, hj, lg);
    gemm_half<0, 4, P0>(H0s, lx, lg, Bf, acc);
    __syncthreads();
    // P2: [pw0-h0 || g0-h1]
    pw0_half<0>(t, acc, c0p, b0sv, wa0v, wb0v, mk, H0s, H1s, OBSs, hj, lg);
    gemm_half<1, 4, P0>(H0s, lx, lg, Bf, acc);
    __syncthreads();
    // P3: [pw0-h1 || g1-h0]
    loadBchunk(w1e, hj, lg, 0, Bp);
    pw0_half<1>(t, acc, c0p, b0sv, wa0v, wb0v, mk, H0s, H1s, OBSs, hj, lg);
    gemm1_half<0>(H1s, lx, lg, hj, w1e, Bp, Bq, acc);
    __syncthreads();
    // P4: [pw1-h0 || g1-h1]
    loadBchunk(w1e, hj, lg, 0, Bp);
    pw1_half<0>(acc, c1p, b1sv, H1s, hj, lg);
    gemm1_half<1>(H1s, lx, lg, hj, w1e, Bp, Bq, acc);
    __syncthreads();
  }

  // ================= transition = D1(0): [pw1-h1(7) || gdec-h0(0)] + XDs init =================
  loadBfull<4>(dwhidb, 128, hj, lg, Bf);
  pw1_half<1>(acc, c1p, b1sv, H1s, hj, lg);
  gemm_half<0, 4, P1>(H1s, lx, lg, Bf, acc);
  if (tid < 256) XDs[tid] = OBSs[(tid >> 1) * 16 + 14 + (tid & 1)];
  __syncthreads();

  // ================= decoder: 12 steps, 2 phases each =================
  #pragma unroll 1
  for (int s = 0; s < 12; ++s){
    float bdv[4], wdx[4], wdy[4];
    #pragma unroll
    for (int g = 0; g < 4; ++g){
      int j = 128 * g + hj;
      bdv[g] = dbsum[s * 512 + j];
      f32x2 w = *(const f32x2*)(dwinb + 2 * (s * 512 + j));
      wdx[g] = w.x; wdy[g] = w.y;
    }
    // D2(s): [pwd-h0(s) || g-h1(s) || oh-h1(s-1)]
    pwd_half<0>(acc, c1p, bdv, wdx, wdy, H1s, XDs, hj, lg);
    gemm_half<1, 4, P1>(H1s, lx, lg, Bf, acc);
    if (s > 0 && wv >= 4) out_head(s - 1, wv, lx, lg, b0, H1s, dwoutb, dbout, XDs, out);
    __syncthreads();
    // D1(s+1): [pwd-h1(s) || g-h0(s+1) || oh-h0(s)]
    if (s < 11){
      loadBfull<4>(dwhidb + (size_t)(s + 1) * 65536, 128, hj, lg, Bf);
      pwd_half<1>(acc, c1p, bdv, wdx, wdy, H1s, XDs, hj, lg);
      gemm_half<0, 4, P1>(H1s, lx, lg, Bf, acc);
      if (wv < 4) out_head(s, wv, lx, lg, b0, H1s, dwoutb, dbout, XDs, out);
      __syncthreads();
    } else {
      pwd_half<1>(acc, c1p, bdv, wdx, wdy, H1s, XDs, hj, lg);
      if (wv < 4) out_head(11, wv, lx, lg, b0, H1s, dwoutb, dbout, XDs, out);
      __syncthreads();
      if (wv >= 4) out_head(11, wv, lx, lg, b0, H1s, dwoutb, dbout, XDs, out);
    }
  }
}

// ---------------- launch ----------------
extern "C" void kernel_launch(void* const* d_in, const int* in_sizes, int n_in,
                              void* d_out, int out_size, void* d_ws, size_t ws_size,
                              hipStream_t stream){
  (void)in_sizes; (void)n_in; (void)out_size; (void)ws_size;
  const float* obs   = (const float*)d_in[0];
  const float* wih0  = (const float*)d_in[1];
  const float* whh0  = (const float*)d_in[2];
  const float* bih0  = (const float*)d_in[3];
  const float* bhh0  = (const float*)d_in[4];
  const float* wih1  = (const float*)d_in[5];
  const float* whh1  = (const float*)d_in[6];
  const float* bih1  = (const float*)d_in[7];
  const float* bhh1  = (const float*)d_in[8];
  const float* din_wmu  = (const float*)d_in[9];
  const float* din_wrho = (const float*)d_in[10];
  const float* din_bmu  = (const float*)d_in[11];
  const float* din_brho = (const float*)d_in[12];
  const float* dhid_wmu  = (const float*)d_in[13];
  const float* dhid_wrho = (const float*)d_in[14];
  const float* dhid_bmu  = (const float*)d_in[15];
  const float* dhid_brho = (const float*)d_in[16];
  const float* out_wmu  = (const float*)d_in[17];
  const float* out_wrho = (const float*)d_in[18];
  const float* out_bmu  = (const float*)d_in[19];
  const float* out_brho = (const float*)d_in[20];

  char* wsb = (char*)d_ws;
  ushort_t* whh0b  = (ushort_t*)(wsb + 0);         // 131072
  ushort_t* w1e    = (ushort_t*)(wsb + 131072);    // 262144
  float*    wx0s   = (float*)(wsb + 393216);       // 4096
  float*    b0s    = (float*)(wsb + 397312);       // 2048
  float*    b1s    = (float*)(wsb + 399360);       // 2048
  ushort_t* dwhidb = (ushort_t*)(wsb + 401408);    // 1572864
  float*    dwinb  = (float*)(wsb + 1974272);      // 49152
  float*    dbsum  = (float*)(wsb + 2023424);      // 24576
  ushort_t* dwoutb = (ushort_t*)(wsb + 2048000);   // 49152
  float*    dbout  = (float*)(wsb + 2097152);      // 192
  unsigned* maskT  = (unsigned*)(wsb + 2097344);   // 4194304

  // zero the KL accumulator slot (prep atomically adds into it)
  hipMemsetAsync((float*)d_out + 1572864, 0, 4, stream);

  prep_all<<<8380, 256, 0, stream>>>(
      wih0, whh0, bih0, bhh0, wih1, whh1, bih1, bhh1,
      din_wmu, din_wrho, din_bmu, din_brho,
      dhid_wmu, dhid_wrho, dhid_bmu, dhid_brho,
      out_wmu, out_wrho, out_bmu, out_brho,
      whh0b, w1e, wx0s, b0s, b1s, dwhidb, dwinb, dbsum, dwoutb, dbout,
      maskT, (float*)d_out);

  lstm_main<<<256, 512, 0, stream>>>(obs, whh0b, w1e, wx0s, b0s, b1s,
                                     dwhidb, dwinb, dbsum, dwoutb, dbout,
                                     maskT, (float*)d_out);
}

// Round 6
// 836.777 us; speedup vs baseline: 1.4143x; 1.1456x over previous
//
#include <hip/hip_runtime.h>

typedef float f32x4 __attribute__((ext_vector_type(4)));
typedef float f32x2 __attribute__((ext_vector_type(2)));
typedef short bf16x8 __attribute__((ext_vector_type(8)));
typedef unsigned short ushort_t;
typedef unsigned int uint_t;

#define LOG2E  1.442695041f
#define LOG2E2 2.885390082f

// ---------------- Threefry-2x32 (20 rounds), exact JAX semantics (verified r1) ----------------
__device__ __forceinline__ unsigned rotl32(unsigned x, unsigned r){ return (x << r) | (x >> (32u - r)); }

__device__ __forceinline__ void tf2x32(unsigned k0, unsigned k1, unsigned c0, unsigned c1,
                                       unsigned &o0, unsigned &o1){
  unsigned ks2 = k0 ^ k1 ^ 0x1BD11BDAu;
  unsigned x0 = c0 + k0, x1 = c1 + k1;
#define TFR(r) { x0 += x1; x1 = rotl32(x1, r); x1 ^= x0; }
  TFR(13) TFR(15) TFR(26) TFR(6)
  x0 += k1;  x1 += ks2 + 1u;
  TFR(17) TFR(29) TFR(16) TFR(24)
  x0 += ks2; x1 += k0 + 2u;
  TFR(13) TFR(15) TFR(26) TFR(6)
  x0 += k0;  x1 += k1 + 3u;
  TFR(17) TFR(29) TFR(16) TFR(24)
  x0 += k1;  x1 += ks2 + 4u;
  TFR(13) TFR(15) TFR(26) TFR(6)
  x0 += ks2; x1 += k0 + 5u;
#undef TFR
  o0 = x0; o1 = x1;
}

__device__ __forceinline__ float bits_to_u01(unsigned bits){
  return __uint_as_float((bits >> 9) | 0x3f800000u) - 1.0f;
}

// XLA ErfInv32 (Giles polynomial) — verified r1
__device__ __forceinline__ float erfinv_f(float x){
  float w = -log1pf(-x * x);
  float p;
  if (w < 5.0f){
    w -= 2.5f;
    p = 2.81022636e-08f;
    p = 3.43273939e-07f + p * w;
    p = -3.5233877e-06f + p * w;
    p = -4.39150654e-06f + p * w;
    p = 0.00021858087f + p * w;
    p = -0.00125372503f + p * w;
    p = -0.00417768164f + p * w;
    p = 0.246640727f + p * w;
    p = 1.50140941f + p * w;
  } else {
    w = sqrtf(w) - 3.0f;
    p = -0.000200214257f;
    p = 0.000100950558f + p * w;
    p = 0.00134934322f + p * w;
    p = -0.00367342844f + p * w;
    p = 0.00573950773f + p * w;
    p = -0.0076224613f + p * w;
    p = 0.00943887047f + p * w;
    p = 1.00167406f + p * w;
    p = 2.83297682f + p * w;
  }
  return p * x;
}

__device__ __forceinline__ ushort_t f2bf(float f){
  unsigned u = __float_as_uint(f);
  unsigned r = u + 0x7fffu + ((u >> 16) & 1u);
  return (ushort_t)(r >> 16);
}

__device__ __forceinline__ float norm_draw(unsigned sk0, unsigned sk1, unsigned g, unsigned e){
  unsigned gk0, gk1, b0, b1;
  tf2x32(sk0, sk1, 0u, g, gk0, gk1);
  tf2x32(gk0, gk1, 0u, e, b0, b1);
  unsigned bits = b0 ^ b1;
  float u01 = bits_to_u01(bits);
  const float LO = __uint_as_float(0xBF7FFFFFu);
  float u = u01 * 2.0f + LO;
  u = fmaxf(LO, u);
  return 1.41421356237f * erfinv_f(u);
}

__device__ __forceinline__ float softplus_f(float r){ return log1pf(expf(r)); }
__device__ __forceinline__ float gscale(int gate){ return gate == 2 ? LOG2E2 : LOG2E; }

// ---------------- fast device math for main kernel ----------------
__device__ __forceinline__ float fexp2(float x){
  float r;
  asm("v_exp_f32 %0, %1" : "=v"(r) : "v"(x));
  return r;
}
__device__ __forceinline__ float frcp(float x){ return __builtin_amdgcn_rcpf(x); }

// gates are PRE-SCALED: i,f,o by log2e; g by 2*log2e (folded into weights in prep)
__device__ __forceinline__ float lstm_act(float gi, float gf, float gg, float go, float& c){
  float Ef = fexp2(gf);
  float sf = Ef * frcp(1.0f + Ef);
  float EiN = fexp2(-gi);
  float Eg  = fexp2(gg);
  float cn = sf * c + (Eg - 1.0f) * frcp((1.0f + EiN) * (Eg + 1.0f));
  c = cn;
  float EoN = fexp2(-go);
  float Ec  = fexp2(cn * LOG2E2);
  return (Ec - 1.0f) * frcp((1.0f + EoN) * (Ec + 1.0f));
}

__device__ __forceinline__ float cp_lo(unsigned w){ return __uint_as_float(w << 16); }
__device__ __forceinline__ float cp_hi(unsigned w){ return __uint_as_float(w & 0xFFFF0000u); }
__device__ __forceinline__ unsigned cp_pack(float lo, float hi){
  return (__float_as_uint(hi) & 0xFFFF0000u) | (__float_as_uint(lo) >> 16);
}

// ---------------- geometry ----------------
constexpr int P0 = 136;   // H0 pitch (elems): h0[128] + pad
constexpr int P1 = 264;   // H1 pitch: h1[128] | hd/x[128] | pad

// ---------------- fused prep ----------------
__global__ void prep_all(
    const float* __restrict__ wih0,  const float* __restrict__ whh0,
    const float* __restrict__ bih0,  const float* __restrict__ bhh0,
    const float* __restrict__ wih1,  const float* __restrict__ whh1,
    const float* __restrict__ bih1,  const float* __restrict__ bhh1,
    const float* __restrict__ din_wmu, const float* __restrict__ din_wrho,
    const float* __restrict__ din_bmu, const float* __restrict__ din_brho,
    const float* __restrict__ dhid_wmu, const float* __restrict__ dhid_wrho,
    const float* __restrict__ dhid_bmu, const float* __restrict__ dhid_brho,
    const float* __restrict__ out_wmu, const float* __restrict__ out_wrho,
    const float* __restrict__ out_bmu, const float* __restrict__ out_brho,
    ushort_t* __restrict__ whh0b, ushort_t* __restrict__ w1e,
    float* __restrict__ wx0s, float* __restrict__ b0s, float* __restrict__ b1s,
    ushort_t* __restrict__ dwhidb, float* __restrict__ dwinb, float* __restrict__ dbsum,
    ushort_t* __restrict__ dwoutb, float* __restrict__ dbout,
    unsigned* __restrict__ maskM, float* __restrict__ out){
  const int blk = blockIdx.x, tid = threadIdx.x;

  if (blk < 4096){
    // dropout mask, BLOCK-MAJOR: word = mb*4096 + t*512 + hj*4 + bw, bit i -> batch mb*128+bw*32+i
    unsigned w = blk * 256u + tid;
    unsigned mb = w >> 12, t = (w >> 9) & 7u, hj = (w >> 2) & 127u, bw = w & 3u;
    unsigned word = 0;
    #pragma unroll 4
    for (int i = 0; i < 32; ++i){
      unsigned ctr = (mb * 128u + bw * 32u + i) * 1024u + t * 128u + hj;  // JAX flat idx b*1024+t*128+h
      unsigned o0, o1;
      tf2x32(0u, 1u, 0u, ctr, o0, o1);
      float u = bits_to_u01(o0 ^ o1);
      word |= (u < 0.9f ? 1u : 0u) << i;
    }
    maskM[w] = word;
  } else if (blk < 4872){
    int idx = (blk - 4096) * 256 + tid;   // < 198656 exact
    if (idx < 65536){
      int row = idx >> 7;
      whh0b[idx] = f2bf(whh0[idx] * gscale(row >> 7));
    } else if (idx < 196608){
      int j = idx - 65536;
      int row = j >> 8, col = j & 255;
      float v = col < 128 ? whh1[row * 128 + col] : wih1[row * 128 + (col - 128)];
      w1e[j] = f2bf(v * gscale(row >> 7));
    } else if (idx < 197632){
      int j = idx - 196608;   // < 1024, row = j>>1
      wx0s[j] = wih0[j] * gscale(j >> 8);
    } else if (idx < 198144){
      int j = idx - 197632;
      b0s[j] = (bih0[j] + bhh0[j]) * gscale(j >> 7);
    } else {
      int j = idx - 198144;
      b1s[j] = (bih1[j] + bhh1[j]) * gscale(j >> 7);
    }
  } else if (blk < 8113){
    int idx = (blk - 4872) * 256 + tid;
    if (idx < 829488){
      int s = idx / 69124, r = idx - s * 69124;
      unsigned sk0, sk1;
      tf2x32(0u, 2u, 0u, (unsigned)s, sk0, sk1);   // split(key(2), 12)
      if (r < 65536){
        int row = r >> 7;
        float v = dhid_wmu[r] + softplus_f(dhid_wrho[r]) * norm_draw(sk0, sk1, 2u, (unsigned)r);
        dwhidb[s * 65536 + r] = f2bf(v * gscale(row >> 7));
      } else if (r < 66560){
        int j = r - 65536;   // row = j>>1
        float v = din_wmu[j] + softplus_f(din_wrho[j]) * norm_draw(sk0, sk1, 0u, (unsigned)j);
        dwinb[s * 1024 + j] = v * gscale(j >> 8);
      } else if (r < 67072){
        int j = r - 66560;
        float v1 = din_bmu[j]  + softplus_f(din_brho[j])  * norm_draw(sk0, sk1, 1u, (unsigned)j);
        float v2 = dhid_bmu[j] + softplus_f(dhid_brho[j]) * norm_draw(sk0, sk1, 3u, (unsigned)j);
        dbsum[s * 512 + j] = (v1 + v2) * gscale(j >> 7);
      } else if (r < 69120){
        int j = r - 67072;
        ushort_t v = 0;
        if (j < 512)
          v = f2bf(out_wmu[j] + softplus_f(out_wrho[j]) * norm_draw(sk0, sk1, 4u, (unsigned)j));
        dwoutb[s * 2048 + j] = v;
      } else {
        int j = r - 69120;
        dbout[s * 4 + j] = out_bmu[j] + softplus_f(out_brho[j]) * norm_draw(sk0, sk1, 5u, (unsigned)j);
      }
    }
  } else {
    // KL: 267 blocks, atomicAdd into out[1572864] (zeroed by hipMemsetAsync)
    int idx = (blk - 8113) * 256 + tid;
    float s = 0.f;
    if (idx < 68100){
      float mu, rho;
      if (idx < 1024){ mu = din_wmu[idx]; rho = din_wrho[idx]; }
      else if (idx < 1536){ mu = din_bmu[idx-1024]; rho = din_brho[idx-1024]; }
      else if (idx < 67072){ mu = dhid_wmu[idx-1536]; rho = dhid_wrho[idx-1536]; }
      else if (idx < 67584){ mu = dhid_bmu[idx-67072]; rho = dhid_brho[idx-67072]; }
      else if (idx < 68096){ mu = out_wmu[idx-67584]; rho = out_wrho[idx-67584]; }
      else { mu = out_bmu[idx-68096]; rho = out_brho[idx-68096]; }
      float stdv = softplus_f(rho);
      s = logf(0.1f / stdv) + (stdv * stdv + mu * mu) * 50.0f - 0.5f;
    }
    __shared__ float red[256];
    red[tid] = s;
    __syncthreads();
    for (int off = 128; off > 0; off >>= 1){
      if (tid < off) red[tid] += red[tid + off];
      __syncthreads();
    }
    if (tid == 0) atomicAdd(out + 1572864, red[0]);
  }
}

// ---------------- GEMM helpers: streaming B, 16+16-reg ping-pong ----------------
__device__ __forceinline__ void preB(const ushort_t* __restrict__ W, int WROW,
                                     int hj, int lg, bf16x8 (&B)[4]){
  const ushort_t* wp = W + (size_t)hj * WROW + 8 * lg;
  #pragma unroll
  for (int g = 0; g < 4; ++g)
    B[g] = *(const bf16x8*)(wp + (size_t)(128 * g) * WROW);
}

#define ZACC(acc) { _Pragma("unroll") for (int g_=0;g_<4;++g_) _Pragma("unroll") for (int m_=0;m_<4;++m_) acc[g_][m_] = (f32x4){0.f,0.f,0.f,0.f}; }

// K=128 gemm over batch-half H; Bc holds chunk ki=0 (preloaded before the paired pointwise)
template<int H, int P>
__device__ __forceinline__ void gemm_w128(const ushort_t* __restrict__ Hl,
                                          const ushort_t* __restrict__ W,
                                          int lx, int lg, int hj,
                                          f32x4 (&acc)[4][4], bf16x8 (&Bc)[4]){
  ZACC(acc);
  const ushort_t* wp = W + (size_t)hj * 128 + 8 * lg;
  #pragma unroll
  for (int ki = 0; ki < 4; ++ki){
    bf16x8 Bn[4];
    if (ki < 3){
      #pragma unroll
      for (int g = 0; g < 4; ++g)
        Bn[g] = *(const bf16x8*)(wp + (size_t)(128 * g) * 128 + 32 * (ki + 1));
    }
    #pragma unroll
    for (int m = 0; m < 4; ++m){
      bf16x8 a = *(const bf16x8*)(Hl + (64 * H + 16 * m + lx) * P + 32 * ki + 8 * lg);
      #pragma unroll
      for (int g = 0; g < 4; ++g)
        acc[g][m] = __builtin_amdgcn_mfma_f32_16x16x32_bf16(a, Bc[g], acc[g][m], 0, 0, 0);
    }
    if (ki < 3){
      #pragma unroll
      for (int g = 0; g < 4; ++g) Bc[g] = Bn[g];
    }
  }
}

// K=256 gemm (w1e: [512][256]) over batch-half H of H1s ([h1|hd] cols 0..255)
template<int H>
__device__ __forceinline__ void gemm_w256(const ushort_t* __restrict__ H1,
                                          const ushort_t* __restrict__ W,
                                          int lx, int lg, int hj,
                                          f32x4 (&acc)[4][4], bf16x8 (&Bc)[4]){
  ZACC(acc);
  const ushort_t* wp = W + (size_t)hj * 256 + 8 * lg;
  #pragma unroll
  for (int ki = 0; ki < 8; ++ki){
    bf16x8 Bn[4];
    if (ki < 7){
      #pragma unroll
      for (int g = 0; g < 4; ++g)
        Bn[g] = *(const bf16x8*)(wp + (size_t)(128 * g) * 256 + 32 * (ki + 1));
    }
    #pragma unroll
    for (int m = 0; m < 4; ++m){
      bf16x8 a = *(const bf16x8*)(H1 + (64 * H + 16 * m + lx) * P1 + 32 * ki + 8 * lg);
      #pragma unroll
      for (int g = 0; g < 4; ++g)
        acc[g][m] = __builtin_amdgcn_mfma_f32_16x16x32_bf16(a, Bc[g], acc[g][m], 0, 0, 0);
    }
    if (ki < 7){
      #pragma unroll
      for (int g = 0; g < 4; ++g) Bc[g] = Bn[g];
    }
  }
}

// ---------------- pointwise halves (identical to r4, which passed) ----------------
template<int H>
__device__ __forceinline__ void pw0_half(int t, f32x4 (&acc)[4][4], unsigned* c0p,
    const float (&bv)[4], const float (&wav)[4], const float (&wbv)[4], uint4 mk,
    ushort_t* __restrict__ H0, ushort_t* __restrict__ H1, const float* __restrict__ OBSs,
    int hj, int lg){
  #pragma unroll
  for (int m = 0; m < 4; ++m){
    unsigned cwA = c0p[H*8 + m*2], cwB = c0p[H*8 + m*2 + 1];
    float cf0 = cp_lo(cwA), cf1 = cp_hi(cwA), cf2 = cp_lo(cwB), cf3 = cp_hi(cwB);
    const int wsel = H*2 + (m >> 1);
    unsigned mkw = wsel == 0 ? mk.x : wsel == 1 ? mk.y : wsel == 2 ? mk.z : mk.w;
    #pragma unroll
    for (int e = 0; e < 4; ++e){
      float& cf = e == 0 ? cf0 : e == 1 ? cf1 : e == 2 ? cf2 : cf3;
      int row = 64*H + 16*m + 4*lg + e;
      f32x2 xv = *(const f32x2*)(OBSs + row * 16 + 2 * t);
      float gi = acc[0][m][e] + bv[0] + xv.x * wav[0] + xv.y * wbv[0];
      float gf = acc[1][m][e] + bv[1] + xv.x * wav[1] + xv.y * wbv[1];
      float gg = acc[2][m][e] + bv[2] + xv.x * wav[2] + xv.y * wbv[2];
      float go = acc[3][m][e] + bv[3] + xv.x * wav[3] + xv.y * wbv[3];
      float hv = lstm_act(gi, gf, gg, go, cf);
      H0[row * P0 + hj] = f2bf(hv);
      unsigned keep = (mkw >> (((m & 1) << 4) + 4 * lg + e)) & 1u;
      H1[row * P1 + 128 + hj] = keep ? f2bf(hv * (1.0f / 0.9f)) : (ushort_t)0;
    }
    c0p[H*8 + m*2]     = cp_pack(cf0, cf1);
    c0p[H*8 + m*2 + 1] = cp_pack(cf2, cf3);
  }
}

template<int H>
__device__ __forceinline__ void pw1_half(f32x4 (&acc)[4][4], unsigned* c1p,
    const float (&bv)[4], ushort_t* __restrict__ H1, int hj, int lg){
  #pragma unroll
  for (int m = 0; m < 4; ++m){
    unsigned cwA = c1p[H*8 + m*2], cwB = c1p[H*8 + m*2 + 1];
    float cf0 = cp_lo(cwA), cf1 = cp_hi(cwA), cf2 = cp_lo(cwB), cf3 = cp_hi(cwB);
    #pragma unroll
    for (int e = 0; e < 4; ++e){
      float& cf = e == 0 ? cf0 : e == 1 ? cf1 : e == 2 ? cf2 : cf3;
      int row = 64*H + 16*m + 4*lg + e;
      float gi = acc[0][m][e] + bv[0];
      float gf = acc[1][m][e] + bv[1];
      float gg = acc[2][m][e] + bv[2];
      float go = acc[3][m][e] + bv[3];
      float hv = lstm_act(gi, gf, gg, go, cf);
      H1[row * P1 + hj] = f2bf(hv);
    }
    c1p[H*8 + m*2]     = cp_pack(cf0, cf1);
    c1p[H*8 + m*2 + 1] = cp_pack(cf2, cf3);
  }
}

template<int H>
__device__ __forceinline__ void pwd_half(f32x4 (&acc)[4][4], unsigned* c1p,
    const float (&bv)[4], const float (&wav)[4], const float (&wbv)[4],
    ushort_t* __restrict__ H1, const float* __restrict__ XDs, int hj, int lg){
  #pragma unroll
  for (int m = 0; m < 4; ++m){
    unsigned cwA = c1p[H*8 + m*2], cwB = c1p[H*8 + m*2 + 1];
    float cf0 = cp_lo(cwA), cf1 = cp_hi(cwA), cf2 = cp_lo(cwB), cf3 = cp_hi(cwB);
    #pragma unroll
    for (int e = 0; e < 4; ++e){
      float& cf = e == 0 ? cf0 : e == 1 ? cf1 : e == 2 ? cf2 : cf3;
      int row = 64*H + 16*m + 4*lg + e;
      f32x2 xv = *(const f32x2*)(XDs + 2 * row);
      float gi = acc[0][m][e] + bv[0] + xv.x * wav[0] + xv.y * wbv[0];
      float gf = acc[1][m][e] + bv[1] + xv.x * wav[1] + xv.y * wbv[1];
      float gg = acc[2][m][e] + bv[2] + xv.x * wav[2] + xv.y * wbv[2];
      float go = acc[3][m][e] + bv[3] + xv.x * wav[3] + xv.y * wbv[3];
      float hv = lstm_act(gi, gf, gg, go, cf);
      H1[row * P1 + hj] = f2bf(hv);
    }
    c1p[H*8 + m*2]     = cp_pack(cf0, cf1);
    c1p[H*8 + m*2 + 1] = cp_pack(cf2, cf3);
  }
}

// ---------------- decoder out-head: per-wave 16-row MFMA tile (builtin) ----------------
__device__ __forceinline__ void out_head(int s, int mt, int lx, int lg, int b0,
    const ushort_t* __restrict__ H1, const ushort_t* __restrict__ dwoutb,
    const float* __restrict__ dbout, float* __restrict__ XDs, float* __restrict__ out){
  const ushort_t* wp = dwoutb + (size_t)s * 2048 + lx * 128 + 8 * lg;
  const ushort_t* hp = H1 + (16 * mt + lx) * P1 + 8 * lg;
  f32x4 accO = {0.f, 0.f, 0.f, 0.f};
  accO = __builtin_amdgcn_mfma_f32_16x16x32_bf16(*(const bf16x8*)(hp),      *(const bf16x8*)(wp),      accO, 0, 0, 0);
  accO = __builtin_amdgcn_mfma_f32_16x16x32_bf16(*(const bf16x8*)(hp + 32), *(const bf16x8*)(wp + 32), accO, 0, 0, 0);
  accO = __builtin_amdgcn_mfma_f32_16x16x32_bf16(*(const bf16x8*)(hp + 64), *(const bf16x8*)(wp + 64), accO, 0, 0, 0);
  accO = __builtin_amdgcn_mfma_f32_16x16x32_bf16(*(const bf16x8*)(hp + 96), *(const bf16x8*)(wp + 96), accO, 0, 0, 0);
  if (lx < 4){
    float bo = dbout[s * 4 + lx];
    #pragma unroll
    for (int e = 0; e < 4; ++e){
      int row = 16 * mt + 4 * lg + e;
      float v = accO[e] + bo;
      int gb = b0 + row;
      if (lx < 2){
        out[gb * 24 + s * 2 + lx] = v;
        XDs[2 * row + lx] = v;             // mu feedback
      } else {
        out[786432 + gb * 24 + s * 2 + (lx - 2)] = fminf(fmaxf(v, -4.0f), 2.0f);
      }
    }
  }
}

// ---------------- main fused kernel: 512 thr (8 waves), BT=128, grid 256 (1 block/CU) ----------------
// Register budget: 2 waves/SIMD -> 256 TOTAL (arch+acc unified). Design: acc 64 + B 32 + ~100 misc.
__global__ __launch_bounds__(512, 2) void lstm_main(
    const float* __restrict__ obs,
    const ushort_t* __restrict__ whh0b,   // [512][128] scaled
    const ushort_t* __restrict__ w1e,     // [512][256] scaled (whh1|wih1)
    const float* __restrict__ wx0s,       // [512][2] scaled
    const float* __restrict__ b0s,        // [512] scaled
    const float* __restrict__ b1s,        // [512] scaled
    const ushort_t* __restrict__ dwhidb,  // [12][512][128] scaled
    const float* __restrict__ dwinb,      // [12][512][2] scaled
    const float* __restrict__ dbsum,      // [12][512] scaled
    const ushort_t* __restrict__ dwoutb,  // [12][16][128] (unscaled, rows 4-15 = 0)
    const float* __restrict__ dbout,      // [12][4]
    const unsigned* __restrict__ maskM,   // [256][8][128][4] block-major
    float* __restrict__ out){
  __shared__ __align__(16) ushort_t H0s[128 * P0];   // 34816 B
  __shared__ __align__(16) ushort_t H1s[128 * P1];   // 67584 B
  __shared__ __align__(16) float OBSs[128 * 16];     // 8192 B
  __shared__ float XDs[256];                         // 1024 B

  const int tid = threadIdx.x;
  const int wv = tid >> 6, l = tid & 63, lx = l & 15, lg = l >> 4;
  const int hj = 16 * wv + lx;
  const int b0 = blockIdx.x * 128;

  // stage obs (2048 f32 = 512 f32x4)
  ((f32x4*)OBSs)[tid] = ((const f32x4*)(obs + (size_t)b0 * 16))[tid];
  {
    uint_t* p = (uint_t*)H0s;
    #pragma unroll 1
    for (int i = tid; i < 128 * P0 / 2; i += 512) p[i] = 0;
    uint_t* q = (uint_t*)H1s;
    #pragma unroll 1
    for (int i = tid; i < 128 * P1 / 2; i += 512) q[i] = 0;
  }

  float b0sv[4], wa0v[4], wb0v[4], b1sv[4];
  #pragma unroll
  for (int g = 0; g < 4; ++g){
    int j = 128 * g + hj;
    b0sv[g] = b0s[j];
    f32x2 w = *(const f32x2*)(wx0s + 2 * j);
    wa0v[g] = w.x; wb0v[g] = w.y;
    b1sv[g] = b1s[j];
  }
  unsigned c0p[16], c1p[16];
  #pragma unroll
  for (int i = 0; i < 16; ++i){ c0p[i] = 0; c1p[i] = 0; }

  f32x4 acc[4][4];
  bf16x8 Bc[4];

  __syncthreads();

  // ================= encoder: 8 steps, 4 phases each =================
  #pragma unroll 1
  for (int t = 0; t < 8; ++t){
    // P1: [pw1-h1(t-1) || g0-h0(t)]
    preB(whh0b, 128, hj, lg, Bc);
    const uint4 mk = *(const uint4*)(maskM + (size_t)blockIdx.x * 4096 + (size_t)t * 512 + (size_t)hj * 4);
    if (t > 0) pw1_half<1>(acc, c1p, b1sv, H1s, hj, lg);
    gemm_w128<0, P0>(H0s, whh0b, lx, lg, hj, acc, Bc);
    __syncthreads();
    // P2: [pw0-h0 || g0-h1]
    preB(whh0b, 128, hj, lg, Bc);
    pw0_half<0>(t, acc, c0p, b0sv, wa0v, wb0v, mk, H0s, H1s, OBSs, hj, lg);
    gemm_w128<1, P0>(H0s, whh0b, lx, lg, hj, acc, Bc);
    __syncthreads();
    // P3: [pw0-h1 || g1-h0]
    preB(w1e, 256, hj, lg, Bc);
    pw0_half<1>(t, acc, c0p, b0sv, wa0v, wb0v, mk, H0s, H1s, OBSs, hj, lg);
    gemm_w256<0>(H1s, w1e, lx, lg, hj, acc, Bc);
    __syncthreads();
    // P4: [pw1-h0 || g1-h1]
    preB(w1e, 256, hj, lg, Bc);
    pw1_half<0>(acc, c1p, b1sv, H1s, hj, lg);
    gemm_w256<1>(H1s, w1e, lx, lg, hj, acc, Bc);
    __syncthreads();
  }

  // ================= transition = D1(0): [pw1-h1(7) || gdec-h0(0)] + XDs init =================
  preB(dwhidb, 128, hj, lg, Bc);
  pw1_half<1>(acc, c1p, b1sv, H1s, hj, lg);
  gemm_w128<0, P1>(H1s, dwhidb, lx, lg, hj, acc, Bc);
  if (tid < 256) XDs[tid] = OBSs[(tid >> 1) * 16 + 14 + (tid & 1)];
  __syncthreads();

  // ================= decoder: 12 steps, 2 phases each =================
  #pragma unroll 1
  for (int s = 0; s < 12; ++s){
    const ushort_t* dw_cur = dwhidb + (size_t)s * 65536;
    float bdv[4], wdx[4], wdy[4];
    #pragma unroll
    for (int g = 0; g < 4; ++g){
      int j = 128 * g + hj;
      bdv[g] = dbsum[s * 512 + j];
      f32x2 w = *(const f32x2*)(dwinb + 2 * (s * 512 + j));
      wdx[g] = w.x; wdy[g] = w.y;
    }
    // D2(s): [pwd-h0(s) || g-h1(s) || oh-h1(s-1)]
    preB(dw_cur, 128, hj, lg, Bc);
    pwd_half<0>(acc, c1p, bdv, wdx, wdy, H1s, XDs, hj, lg);
    gemm_w128<1, P1>(H1s, dw_cur, lx, lg, hj, acc, Bc);
    if (s > 0 && wv >= 4) out_head(s - 1, wv, lx, lg, b0, H1s, dwoutb, dbout, XDs, out);
    __syncthreads();
    // D1(s+1): [pwd-h1(s) || g-h0(s+1) || oh-h0(s)]
    if (s < 11){
      const ushort_t* dw_next = dwhidb + (size_t)(s + 1) * 65536;
      preB(dw_next, 128, hj, lg, Bc);
      pwd_half<1>(acc, c1p, bdv, wdx, wdy, H1s, XDs, hj, lg);
      gemm_w128<0, P1>(H1s, dw_next, lx, lg, hj, acc, Bc);
      if (wv < 4) out_head(s, wv, lx, lg, b0, H1s, dwoutb, dbout, XDs, out);
      __syncthreads();
    } else {
      pwd_half<1>(acc, c1p, bdv, wdx, wdy, H1s, XDs, hj, lg);
      if (wv < 4) out_head(11, wv, lx, lg, b0, H1s, dwoutb, dbout, XDs, out);
      __syncthreads();
      if (wv >= 4) out_head(11, wv, lx, lg, b0, H1s, dwoutb, dbout, XDs, out);
    }
  }
}

// ---------------- launch ----------------
extern "C" void kernel_launch(void* const* d_in, const int* in_sizes, int n_in,
                              void* d_out, int out_size, void* d_ws, size_t ws_size,
                              hipStream_t stream){
  (void)in_sizes; (void)n_in; (void)out_size; (void)ws_size;
  const float* obs   = (const float*)d_in[0];
  const float* wih0  = (const float*)d_in[1];
  const float* whh0  = (const float*)d_in[2];
  const float* bih0  = (const float*)d_in[3];
  const float* bhh0  = (const float*)d_in[4];
  const float* wih1  = (const float*)d_in[5];
  const float* whh1  = (const float*)d_in[6];
  const float* bih1  = (const float*)d_in[7];
  const float* bhh1  = (const float*)d_in[8];
  const float* din_wmu  = (const float*)d_in[9];
  const float* din_wrho = (const float*)d_in[10];
  const float* din_bmu  = (const float*)d_in[11];
  const float* din_brho = (const float*)d_in[12];
  const float* dhid_wmu  = (const float*)d_in[13];
  const float* dhid_wrho = (const float*)d_in[14];
  const float* dhid_bmu  = (const float*)d_in[15];
  const float* dhid_brho = (const float*)d_in[16];
  const float* out_wmu  = (const float*)d_in[17];
  const float* out_wrho = (const float*)d_in[18];
  const float* out_bmu  = (const float*)d_in[19];
  const float* out_brho = (const float*)d_in[20];

  char* wsb = (char*)d_ws;
  ushort_t* whh0b  = (ushort_t*)(wsb + 0);         // 131072
  ushort_t* w1e    = (ushort_t*)(wsb + 131072);    // 262144
  float*    wx0s   = (float*)(wsb + 393216);       // 4096
  float*    b0s    = (float*)(wsb + 397312);       // 2048
  float*    b1s    = (float*)(wsb + 399360);       // 2048
  ushort_t* dwhidb = (ushort_t*)(wsb + 401408);    // 1572864
  float*    dwinb  = (float*)(wsb + 1974272);      // 49152
  float*    dbsum  = (float*)(wsb + 2023424);      // 24576
  ushort_t* dwoutb = (ushort_t*)(wsb + 2048000);   // 49152
  float*    dbout  = (float*)(wsb + 2097152);      // 192
  unsigned* maskM  = (unsigned*)(wsb + 2097344);   // 4194304

  // zero the KL accumulator slot (prep atomically adds into it)
  hipMemsetAsync((float*)d_out + 1572864, 0, 4, stream);

  prep_all<<<8380, 256, 0, stream>>>(
      wih0, whh0, bih0, bhh0, wih1, whh1, bih1, bhh1,
      din_wmu, din_wrho, din_bmu, din_brho,
      dhid_wmu, dhid_wrho, dhid_bmu, dhid_brho,
      out_wmu, out_wrho, out_bmu, out_brho,
      whh0b, w1e, wx0s, b0s, b1s, dwhidb, dwinb, dbsum, dwoutb, dbout,
      maskM, (float*)d_out);

  lstm_main<<<256, 512, 0, stream>>>(obs, whh0b, w1e, wx0s, b0s, b1s,
                                     dwhidb, dwinb, dbsum, dwoutb, dbout,
                                     maskM, (float*)d_out);
}